// Round 6
// baseline (157.779 us; speedup 1.0000x reference)
//
#include <hip/hip_runtime.h>
#include <cstdint>
#include <cstddef>

// Problem constants: B=1024, T=12, D=512
#define Bsz 1024
#define Tsz 12
#define Dsz 512

#define TILE 128   // block tile: 128(j) x 128(i)
#define BK   32    // K-chunk per stage (32 floats = 128 B = 8 x 16B chunks/row)
#define NIB  (Bsz / TILE)   // 8 i-tiles per column

typedef _Float16 f16x8 __attribute__((ext_vector_type(8)));
typedef float    f32x4 __attribute__((ext_vector_type(4)));

// Async global->LDS DMA, 16 B per lane. LDS dest is wave-uniform base +
// lane*16 (m104/m108); the *source* address is per-lane free, which is what
// lets us bank-swizzle the LDS image by choosing which global chunk each
// lane fetches.
__device__ __forceinline__ void async_load16(const float* g, float* l) {
    __builtin_amdgcn_global_load_lds(
        (const __attribute__((address_space(1))) void*)g,
        (__attribute__((address_space(3))) void*)l, 16, 0, 0);
}

// In-register fp32 -> f16 hi/lo split (hi = rne(x), lo = rne(x - hi)).
__device__ __forceinline__ void mk_frag(const f32x4 e0, const f32x4 e1,
                                        f16x8& h, f16x8& l) {
    const float x[8] = {e0[0], e0[1], e0[2], e0[3], e1[0], e1[1], e1[2], e1[3]};
#pragma unroll
    for (int i = 0; i < 8; ++i) {
        const _Float16 hi = (_Float16)x[i];
        h[i] = hi;
        l[i] = (_Float16)(x[i] - (float)hi);
    }
}

// Fused GEMM + tile softmax-partials. dots[t,i,j] = <P[j,t,:], X[i,t,:]>.
// K-loop: async-stage fp32 tiles (swizzled) -> in-register hi/lo split ->
// 3-pass f16 MFMA (hi*hi + hi*lo + lo*hi; lo*lo ~2^-22 relative, dropped).
// Epilogue reduces each 128-row's 128-i slice to (max, argmax, sumexp).
__global__ __launch_bounds__(256) void gemm_fused_kernel(
    const float* __restrict__ X,   // x_future_encoded [B,T,D]
    const float* __restrict__ P,   // predictions      [B,T,D]
    float* __restrict__ pm,        // [Tsz*Bsz*NIB] tile max
    float* __restrict__ ps,        // [Tsz*Bsz*NIB] tile sum exp
    int*   __restrict__ pa,        // [Tsz*Bsz*NIB] tile argmax (global i)
    float* __restrict__ diag)      // [Tsz*Bsz]
{
    const int t  = blockIdx.z;
    const int bx = blockIdx.x;
    const int ib = bx * TILE;           // i tile (n-dim)
    const int jb = blockIdx.y * TILE;   // j tile (m-dim)
    const int tid  = threadIdx.x;
    const int lane = tid & 63;
    const int w    = tid >> 6;          // wave 0..3
    const int jw   = (w & 1) * 64;      // wave j-offset inside tile
    const int iw   = (w >> 1) * 64;     // wave i-offset inside tile
    const int ml   = lane & 15;
    const int quad = lane >> 4;

    // fp32 staging tiles; 16B chunk c of row r lives at slot c ^ (r&7).
    __shared__ float Pt[TILE][BK];
    __shared__ float Xt[TILE][BK];
    __shared__ float sm_m[TILE][2];
    __shared__ float sm_s[TILE][2];
    __shared__ int   sm_a[TILE][2];

    f32x4 acc[4][4];
#pragma unroll
    for (int r = 0; r < 4; ++r)
#pragma unroll
        for (int c = 0; c < 4; ++c) acc[r][c] = (f32x4){0.f, 0.f, 0.f, 0.f};

    const size_t strideRow = (size_t)Tsz * Dsz;  // 6144 floats
    const float* Pbase = P + (size_t)jb * strideRow + (size_t)t * Dsz;
    const float* Xbase = X + (size_t)ib * strideRow + (size_t)t * Dsz;

    // Staging lane constants: each issue stages 8 rows x 8 chunks (16 B).
    const int ri  = lane >> 3;   // row within issue
    const int pch = lane & 7;    // LDS chunk slot this lane fills

    for (int k0 = 0; k0 < Dsz; k0 += BK) {
        // ---- async stage: 32 issues/block (16 P + 16 X), 8 per wave ----
#pragma unroll
        for (int u = 0; u < 8; ++u) {
            const int slot = w * 8 + u;
            const float* base;
            float* ldsb;
            int rowbase;
            if (slot < 16) { rowbase = slot * 8;        base = Pbase; ldsb = &Pt[rowbase][0]; }
            else           { rowbase = (slot - 16) * 8; base = Xbase; ldsb = &Xt[rowbase][0]; }
            const int row = rowbase + ri;
            const int sch = pch ^ (row & 7);   // global chunk this lane fetches
            async_load16(base + (size_t)row * strideRow + k0 + sch * 4, ldsb);
        }
        __syncthreads();   // compiler emits vmcnt(0) drain + barrier

        // ---- fragments: ds_read_b128 x2 per row (chunks 2q, 2q+1 swizzled) ----
        f16x8 ah[4], al[4], bh[4], bl[4];
#pragma unroll
        for (int r = 0; r < 4; ++r) {
            const int row = jw + r * 16 + ml;
            const int sw = row & 7;
            f32x4 e0 = *(const f32x4*)&Pt[row][((2 * quad) ^ sw) * 4];
            f32x4 e1 = *(const f32x4*)&Pt[row][((2 * quad + 1) ^ sw) * 4];
            mk_frag(e0, e1, ah[r], al[r]);
        }
#pragma unroll
        for (int c = 0; c < 4; ++c) {
            const int row = iw + c * 16 + ml;
            const int sw = row & 7;
            f32x4 e0 = *(const f32x4*)&Xt[row][((2 * quad) ^ sw) * 4];
            f32x4 e1 = *(const f32x4*)&Xt[row][((2 * quad + 1) ^ sw) * 4];
            mk_frag(e0, e1, bh[c], bl[c]);
        }

        // ---- MFMA: hi*hi + hi*lo + lo*hi ----
#pragma unroll
        for (int r = 0; r < 4; ++r)
#pragma unroll
            for (int c = 0; c < 4; ++c) {
                acc[r][c] = __builtin_amdgcn_mfma_f32_16x16x32_f16(ah[r], bh[c], acc[r][c], 0, 0, 0);
                acc[r][c] = __builtin_amdgcn_mfma_f32_16x16x32_f16(ah[r], bl[c], acc[r][c], 0, 0, 0);
                acc[r][c] = __builtin_amdgcn_mfma_f32_16x16x32_f16(al[r], bh[c], acc[r][c], 0, 0, 0);
            }
        __syncthreads();
    }

    // ---- diag extraction (only diagonal blocks have i == j elements) ----
    if (ib == jb) {
#pragma unroll
        for (int r = 0; r < 4; ++r)
#pragma unroll
            for (int v = 0; v < 4; ++v) {
                const int row = jw + r * 16 + quad * 4 + v;
#pragma unroll
                for (int c = 0; c < 4; ++c) {
                    const int icol = iw + c * 16 + ml;
                    if (icol == row)
                        diag[(size_t)t * Bsz + jb + row] = acc[r][c][v];
                }
            }
    }

    // ---- per-row (j) partial over this wave's 64-i slice ----
    // C/D layout: acc[r][c][v] sits at row j = jw+r*16+quad*4+v,
    // col i = iw+c*16+ml. Reduce over c and the 16 ml-lanes of each quad.
#pragma unroll
    for (int r = 0; r < 4; ++r)
#pragma unroll
        for (int v = 0; v < 4; ++v) {
            float m = acc[r][0][v];
            int   ai = iw + ml;
#pragma unroll
            for (int c = 1; c < 4; ++c) {
                const float val = acc[r][c][v];
                if (val > m) { m = val; ai = iw + c * 16 + ml; }
            }
#pragma unroll
            for (int off = 1; off < 16; off <<= 1) {
                float om = __shfl_xor(m, off);
                int   oi = __shfl_xor(ai, off);
                if (om > m || (om == m && oi < ai)) { m = om; ai = oi; }
            }
            float s = 0.0f;
#pragma unroll
            for (int c = 0; c < 4; ++c) s += __expf(acc[r][c][v] - m);
#pragma unroll
            for (int off = 1; off < 16; off <<= 1) s += __shfl_xor(s, off);

            if (ml == 0) {
                const int row = jw + r * 16 + quad * 4 + v;
                sm_m[row][iw >> 6] = m;
                sm_s[row][iw >> 6] = s;
                sm_a[row][iw >> 6] = ib + ai;   // global i
            }
        }
    __syncthreads();

    // ---- combine the two wave halves, write tile partials ----
    if (tid < TILE) {
        const int row = tid;
        const float m0 = sm_m[row][0], m1 = sm_m[row][1];
        const float s0 = sm_s[row][0], s1 = sm_s[row][1];
        float M; int A;
        if (m1 > m0) { M = m1; A = sm_a[row][1]; }   // tie -> half 0 (smaller i)
        else         { M = m0; A = sm_a[row][0]; }
        const float S = s0 * __expf(m0 - M) + s1 * __expf(m1 - M);
        const size_t slot = ((size_t)t * Bsz + (jb + row)) * NIB + bx;
        pm[slot] = M;
        ps[slot] = S;
        pa[slot] = A;
    }
}

__global__ void zero_out_kernel(float* out) {
    if (threadIdx.x < 2) out[threadIdx.x] = 0.0f;
}

// One thread per (t,j) column: merge NIB tile partials, 48 block atomics.
__global__ __launch_bounds__(256) void combine_kernel(
    const float* __restrict__ pm,
    const float* __restrict__ ps,
    const int*   __restrict__ pa,
    const float* __restrict__ diag,
    float* __restrict__ out)
{
    const int col = blockIdx.x * 256 + threadIdx.x;   // 0..Tsz*Bsz-1
    const int j = col & (Bsz - 1);

    const size_t base = (size_t)col * NIB;
    float M = pm[base]; int A = pa[base];
#pragma unroll
    for (int b = 1; b < NIB; ++b) {
        const float mb = pm[base + b];
        if (mb > M) { M = mb; A = pa[base + b]; }   // tie -> earlier b = smaller i
    }
    float S = 0.0f;
#pragma unroll
    for (int b = 0; b < NIB; ++b) S += ps[base + b] * __expf(pm[base + b] - M);

    const float lse = M + logf(S);
    float sl = lse - diag[col];
    float sc = (A == j) ? 1.0f : 0.0f;

#pragma unroll
    for (int off = 1; off < 64; off <<= 1) {
        sl += __shfl_xor(sl, off);
        sc += __shfl_xor(sc, off);
    }

    __shared__ float wl[4], wc[4];
    const int w = threadIdx.x >> 6;
    if ((threadIdx.x & 63) == 0) { wl[w] = sl; wc[w] = sc; }
    __syncthreads();
    if (threadIdx.x == 0) {
        const float inv = 1.0f / (float)(Bsz * Tsz);
        atomicAdd(&out[0], (wl[0] + wl[1] + wl[2] + wl[3]) * inv);  // -loss
        atomicAdd(&out[1], (wc[0] + wc[1] + wc[2] + wc[3]) * inv);  // accuracy
    }
}

extern "C" void kernel_launch(void* const* d_in, const int* in_sizes, int n_in,
                              void* d_out, int out_size, void* d_ws, size_t ws_size,
                              hipStream_t stream) {
    const float* P = (const float*)d_in[0];  // predictions [B,T,D]
    const float* X = (const float*)d_in[1];  // x_future_encoded [B,T,D]
    float* out = (float*)d_out;

    const size_t ncol  = (size_t)Bsz * Tsz;          // 12288
    const size_t nslot = ncol * NIB;                 // 98304
    float* pm   = (float*)d_ws;
    float* ps   = pm + nslot;
    int*   pa   = (int*)(ps + nslot);
    float* diag = (float*)(pa + nslot);

    gemm_fused_kernel<<<dim3(NIB, Bsz / TILE, Tsz), dim3(256), 0, stream>>>(
        X, P, pm, ps, pa, diag);

    zero_out_kernel<<<dim3(1), dim3(64), 0, stream>>>(out);

    combine_kernel<<<dim3((int)(ncol / 256)), dim3(256), 0, stream>>>(
        pm, ps, pa, diag, out);
}

// Round 7
// 145.017 us; speedup vs baseline: 1.0880x; 1.0880x over previous
//
#include <hip/hip_runtime.h>
#include <cstdint>
#include <cstddef>

// Problem constants: B=1024, T=12, D=512
#define Bsz 1024
#define Tsz 12
#define Dsz 512

#define TJ 128     // block tile rows (j)
#define TI 64      // block tile cols (i)
#define BK 32      // K-chunk per stage
#define NIB (Bsz / TI)   // 16 i-tiles per column

typedef _Float16 h4    __attribute__((ext_vector_type(4)));
typedef _Float16 f16x8 __attribute__((ext_vector_type(8)));
typedef float    f32x4 __attribute__((ext_vector_type(4)));

// fp32 -> f16 hi/lo split (hi = rne(x), lo = rne(x - hi)); hi*hi / hi*lo /
// lo*hi accumulate in fp32 inside the MFMA; dropped lo*lo ~2^-22 relative.
__device__ __forceinline__ void cvt_store(const float4 v, _Float16* hp, _Float16* lp) {
    _Float16 hx = (_Float16)v.x, hy = (_Float16)v.y,
             hz = (_Float16)v.z, hw = (_Float16)v.w;
    h4 hh = {hx, hy, hz, hw};
    h4 ll = {(_Float16)(v.x - (float)hx), (_Float16)(v.y - (float)hy),
             (_Float16)(v.z - (float)hz), (_Float16)(v.w - (float)hw)};
    *(h4*)hp = hh;
    *(h4*)lp = ll;
}

// Fused GEMM + tile softmax-partials. dots[t,i,j] = <P[j,t,:], X[i,t,:]>.
// 128x64 tile, 4 waves (2j x 2i), acc = 32 regs/wave -> with the 128-reg cap
// from __launch_bounds__(256,4) this gives 4 blocks/CU (vs 2 at 128x128).
__global__ __launch_bounds__(256, 4) void gemm_fused_kernel(
    const float* __restrict__ X,   // x_future_encoded [B,T,D]
    const float* __restrict__ P,   // predictions      [B,T,D]
    float* __restrict__ pm,        // [Tsz*Bsz*NIB] tile max
    float* __restrict__ ps,        // [Tsz*Bsz*NIB] tile sum exp
    int*   __restrict__ pa,        // [Tsz*Bsz*NIB] tile argmax (global i)
    float* __restrict__ diag)      // [Tsz*Bsz]
{
    const int t  = blockIdx.z;
    const int bx = blockIdx.x;
    const int ib = bx * TI;             // i tile (n-dim)
    const int jb = blockIdx.y * TJ;     // j tile (m-dim)
    const int tid  = threadIdx.x;
    const int lane = tid & 63;
    const int w    = tid >> 6;          // wave 0..3
    const int jw   = (w & 1) * 64;      // wave j-offset
    const int iw   = (w >> 1) * 32;     // wave i-offset
    const int ml   = lane & 15;
    const int quad = lane >> 4;

    __shared__ _Float16 Ph[TJ][BK];
    __shared__ _Float16 Pl[TJ][BK];
    __shared__ _Float16 Xh[TI][BK];
    __shared__ _Float16 Xl[TI][BK];
    __shared__ float sm_m[TJ][2];
    __shared__ float sm_s[TJ][2];
    __shared__ int   sm_a[TJ][2];

    f32x4 acc[4][2];
#pragma unroll
    for (int r = 0; r < 4; ++r)
#pragma unroll
        for (int c = 0; c < 2; ++c) acc[r][c] = (f32x4){0.f, 0.f, 0.f, 0.f};

    const size_t strideRow = (size_t)Tsz * Dsz;  // 6144 floats
    const float* Pbase = P + (size_t)jb * strideRow + (size_t)t * Dsz;
    const float* Xbase = X + (size_t)ib * strideRow + (size_t)t * Dsz;

    for (int k0 = 0; k0 < Dsz; k0 += BK) {
        // ---- stage: P 128 rows (4 f4/thread), X 64 rows (2 f4/thread) ----
#pragma unroll
        for (int h = 0; h < 4; ++h) {
            const int idx = tid + h * 256;
            const int row = idx >> 3;
            const int c4  = idx & 7;
            float4 pv = *(const float4*)(Pbase + (size_t)row * strideRow + k0 + c4 * 4);
            cvt_store(pv, &Ph[row][c4 * 4], &Pl[row][c4 * 4]);
        }
#pragma unroll
        for (int h = 0; h < 2; ++h) {
            const int idx = tid + h * 256;
            const int row = idx >> 3;
            const int c4  = idx & 7;
            float4 xv = *(const float4*)(Xbase + (size_t)row * strideRow + k0 + c4 * 4);
            cvt_store(xv, &Xh[row][c4 * 4], &Xl[row][c4 * 4]);
        }
        __syncthreads();

        // ---- fragments ----
        f16x8 ah[4], al[4], bh[2], bl[2];
#pragma unroll
        for (int r = 0; r < 4; ++r) {
            ah[r] = *(const f16x8*)&Ph[jw + r * 16 + ml][quad * 8];
            al[r] = *(const f16x8*)&Pl[jw + r * 16 + ml][quad * 8];
        }
#pragma unroll
        for (int c = 0; c < 2; ++c) {
            bh[c] = *(const f16x8*)&Xh[iw + c * 16 + ml][quad * 8];
            bl[c] = *(const f16x8*)&Xl[iw + c * 16 + ml][quad * 8];
        }

        // ---- MFMA: hi*hi + hi*lo + lo*hi ----
#pragma unroll
        for (int r = 0; r < 4; ++r)
#pragma unroll
            for (int c = 0; c < 2; ++c) {
                acc[r][c] = __builtin_amdgcn_mfma_f32_16x16x32_f16(ah[r], bh[c], acc[r][c], 0, 0, 0);
                acc[r][c] = __builtin_amdgcn_mfma_f32_16x16x32_f16(ah[r], bl[c], acc[r][c], 0, 0, 0);
                acc[r][c] = __builtin_amdgcn_mfma_f32_16x16x32_f16(al[r], bh[c], acc[r][c], 0, 0, 0);
            }
        __syncthreads();
    }

    // ---- diag extraction (global index test; cheap, epilogue-only) ----
#pragma unroll
    for (int r = 0; r < 4; ++r)
#pragma unroll
        for (int v = 0; v < 4; ++v) {
            const int jg = jb + jw + r * 16 + quad * 4 + v;
#pragma unroll
            for (int c = 0; c < 2; ++c) {
                const int ig = ib + iw + c * 16 + ml;
                if (ig == jg) diag[(size_t)t * Bsz + jg] = acc[r][c][v];
            }
        }

    // ---- per-row (j) partial over this wave's 32-i slice ----
    // acc[r][c][v] sits at row j = jw+r*16+quad*4+v, col i = iw+c*16+ml.
#pragma unroll
    for (int r = 0; r < 4; ++r)
#pragma unroll
        for (int v = 0; v < 4; ++v) {
            float m = acc[r][0][v];
            int   ai = iw + ml;
            {
                const float val = acc[r][1][v];
                if (val > m) { m = val; ai = iw + 16 + ml; }
            }
#pragma unroll
            for (int off = 1; off < 16; off <<= 1) {
                float om = __shfl_xor(m, off);
                int   oi = __shfl_xor(ai, off);
                if (om > m || (om == m && oi < ai)) { m = om; ai = oi; }
            }
            float s = __expf(acc[r][0][v] - m) + __expf(acc[r][1][v] - m);
#pragma unroll
            for (int off = 1; off < 16; off <<= 1) s += __shfl_xor(s, off);

            if (ml == 0) {
                const int row = jw + r * 16 + quad * 4 + v;
                sm_m[row][iw >> 5] = m;
                sm_s[row][iw >> 5] = s;
                sm_a[row][iw >> 5] = ib + ai;   // global i
            }
        }
    __syncthreads();

    // ---- combine the two i-halves, write tile partials ----
    if (tid < TJ) {
        const int row = tid;
        const float m0 = sm_m[row][0], m1 = sm_m[row][1];
        const float s0 = sm_s[row][0], s1 = sm_s[row][1];
        float M; int A;
        if (m1 > m0) { M = m1; A = sm_a[row][1]; }   // tie -> half 0 (smaller i)
        else         { M = m0; A = sm_a[row][0]; }
        const float S = s0 * __expf(m0 - M) + s1 * __expf(m1 - M);
        const size_t slot = ((size_t)t * Bsz + (jb + row)) * NIB + bx;
        pm[slot] = M;
        ps[slot] = S;
        pa[slot] = A;
    }
}

__global__ void zero_out_kernel(float* out) {
    if (threadIdx.x < 2) out[threadIdx.x] = 0.0f;
}

// One thread per (t,j) column: merge NIB tile partials, 48 block atomics.
__global__ __launch_bounds__(256) void combine_kernel(
    const float* __restrict__ pm,
    const float* __restrict__ ps,
    const int*   __restrict__ pa,
    const float* __restrict__ diag,
    float* __restrict__ out)
{
    const int col = blockIdx.x * 256 + threadIdx.x;   // 0..Tsz*Bsz-1
    const int j = col & (Bsz - 1);

    const size_t base = (size_t)col * NIB;
    float M = pm[base]; int A = pa[base];
#pragma unroll
    for (int b = 1; b < NIB; ++b) {
        const float mb = pm[base + b];
        if (mb > M) { M = mb; A = pa[base + b]; }   // tie -> earlier b = smaller i
    }
    float S = 0.0f;
#pragma unroll
    for (int b = 0; b < NIB; ++b) S += ps[base + b] * __expf(pm[base + b] - M);

    const float lse = M + logf(S);
    float sl = lse - diag[col];
    float sc = (A == j) ? 1.0f : 0.0f;

#pragma unroll
    for (int off = 1; off < 64; off <<= 1) {
        sl += __shfl_xor(sl, off);
        sc += __shfl_xor(sc, off);
    }

    __shared__ float wl[4], wc[4];
    const int w = threadIdx.x >> 6;
    if ((threadIdx.x & 63) == 0) { wl[w] = sl; wc[w] = sc; }
    __syncthreads();
    if (threadIdx.x == 0) {
        const float inv = 1.0f / (float)(Bsz * Tsz);
        atomicAdd(&out[0], (wl[0] + wl[1] + wl[2] + wl[3]) * inv);  // -loss
        atomicAdd(&out[1], (wc[0] + wc[1] + wc[2] + wc[3]) * inv);  // accuracy
    }
}

extern "C" void kernel_launch(void* const* d_in, const int* in_sizes, int n_in,
                              void* d_out, int out_size, void* d_ws, size_t ws_size,
                              hipStream_t stream) {
    const float* P = (const float*)d_in[0];  // predictions [B,T,D]
    const float* X = (const float*)d_in[1];  // x_future_encoded [B,T,D]
    float* out = (float*)d_out;

    const size_t ncol  = (size_t)Bsz * Tsz;          // 12288
    const size_t nslot = ncol * NIB;                 // 196608
    float* pm   = (float*)d_ws;
    float* ps   = pm + nslot;
    int*   pa   = (int*)(ps + nslot);
    float* diag = (float*)(pa + nslot);

    gemm_fused_kernel<<<dim3(NIB, Bsz / TJ, Tsz), dim3(256), 0, stream>>>(
        X, P, pm, ps, pa, diag);

    zero_out_kernel<<<dim3(1), dim3(64), 0, stream>>>(out);

    combine_kernel<<<dim3((int)(ncol / 256)), dim3(256), 0, stream>>>(
        pm, ps, pa, diag, out);
}